// Round 2
// baseline (1132.592 us; speedup 1.0000x reference)
//
#include <hip/hip_runtime.h>
#include <stdint.h>

#define DIM 256
#define SEQ 8192
#define BATCH 32
#define ROWS (BATCH * SEQ)    // 262144
#define CS 128                // scan chunk length
#define NCH (SEQ / CS)        // 64 chunks per sequence

typedef float f32x4 __attribute__((ext_vector_type(4)));
typedef short short8 __attribute__((ext_vector_type(8)));
typedef unsigned short u16;
typedef u16 ushort8 __attribute__((ext_vector_type(8)));

__device__ __forceinline__ u16 f2bf(float f) {
  uint32_t u = __float_as_uint(f);
  u += 0x7fffu + ((u >> 16) & 1u);   // round-to-nearest-even
  return (u16)(u >> 16);
}

// One-time: W[l][k][d] f32 -> Wt[mat][d][k] bf16, mat = {Wz l0, Wz l1, Wh l0, Wh l1}
__global__ void wt_kernel(const float* __restrict__ Wz, const float* __restrict__ Wh,
                          u16* __restrict__ Wt) {
  int idx = blockIdx.x * 256 + threadIdx.x;   // 4*65536
  int k = idx & 255;
  int d = (idx >> 8) & 255;
  int mat = idx >> 16;
  const float* src = (mat < 2 ? Wz : Wh) + (size_t)(mat & 1) * 65536;
  Wt[idx] = f2bf(src[k * 256 + d]);
}

// GEMM: 128-row tile x (DH z-cols + DH h-cols), K=256.
// MODE 0: A = emb[x[row]] (f32 gather->bf16). MODE 1: A = h1 (bf16).
// 4 waves, each owns 32 rows x DH cols. Epilogue -> ab[row][dloc] = (1-z, z*htilde).
template<int MODE, int DH>
__global__ __launch_bounds__(256, 2)
void gemm_kernel(const int* __restrict__ x, const float* __restrict__ emb,
                 const u16* __restrict__ h1,
                 const u16* __restrict__ Wzt, const u16* __restrict__ Wht,
                 const float* __restrict__ bz, const float* __restrict__ bh,
                 int dh0, float2* __restrict__ ab)
{
  constexpr int NI = DH / 16;
  __shared__ __align__(16) u16 As[128 * 40];   // [m][k], rows padded to 40 shorts (80B)
  __shared__ __align__(16) u16 Bzs[DH * 40];   // [d][k] (weights pre-transposed)
  __shared__ __align__(16) u16 Bhs[DH * 40];
  __shared__ int toks[128];

  const int tid = threadIdx.x;
  const int lane = tid & 63;
  const int wid = tid >> 6;                    // wave 0..3 -> rows wid*32..+31
  const int rows0 = blockIdx.x * 128;
  const int sm = tid >> 1;                     // A-staging row 0..127
  const int sk = (tid & 1) * 16;               // A-staging k offset 0/16
  const int l15 = lane & 15, lg = lane >> 4;

  if (MODE == 0 && tid < 128) toks[tid] = x[rows0 + tid];

  f32x4 accz[2][NI], acch[2][NI];
  #pragma unroll
  for (int i = 0; i < 2; i++)
    #pragma unroll
    for (int j = 0; j < NI; j++) {
      f32x4 zz = {0.f, 0.f, 0.f, 0.f};
      accz[i][j] = zz; acch[i][j] = zz;
    }

  for (int kt = 0; kt < 8; kt++) {
    const int kk0 = kt * 32;
    __syncthreads();
    if (MODE == 0) {
      const float* arow = emb + (size_t)toks[sm] * DIM + kk0 + sk;
      float4 a0 = *(const float4*)(arow + 0);
      float4 a1 = *(const float4*)(arow + 4);
      float4 a2 = *(const float4*)(arow + 8);
      float4 a3 = *(const float4*)(arow + 12);
      ushort8 p0, p1;
      p0[0]=f2bf(a0.x); p0[1]=f2bf(a0.y); p0[2]=f2bf(a0.z); p0[3]=f2bf(a0.w);
      p0[4]=f2bf(a1.x); p0[5]=f2bf(a1.y); p0[6]=f2bf(a1.z); p0[7]=f2bf(a1.w);
      p1[0]=f2bf(a2.x); p1[1]=f2bf(a2.y); p1[2]=f2bf(a2.z); p1[3]=f2bf(a2.w);
      p1[4]=f2bf(a3.x); p1[5]=f2bf(a3.y); p1[6]=f2bf(a3.z); p1[7]=f2bf(a3.w);
      *(ushort8*)&As[sm * 40 + sk]     = p0;
      *(ushort8*)&As[sm * 40 + sk + 8] = p1;
    } else {
      const u16* arow = h1 + (size_t)(rows0 + sm) * DIM + kk0 + sk;
      *(ushort8*)&As[sm * 40 + sk]     = *(const ushort8*)(arow);
      *(ushort8*)&As[sm * 40 + sk + 8] = *(const ushort8*)(arow + 8);
    }
    if (tid < 2 * DH) {
      const int r = tid >> 1, k2 = (tid & 1) * 16;
      const u16* zrow = Wzt + (size_t)(dh0 + r) * DIM + kk0 + k2;
      *(ushort8*)&Bzs[r * 40 + k2]     = *(const ushort8*)(zrow);
      *(ushort8*)&Bzs[r * 40 + k2 + 8] = *(const ushort8*)(zrow + 8);
    } else if (tid < 4 * DH) {
      const int t2 = tid - 2 * DH;
      const int r = t2 >> 1, k2 = (t2 & 1) * 16;
      const u16* hrow = Wht + (size_t)(dh0 + r) * DIM + kk0 + k2;
      *(ushort8*)&Bhs[r * 40 + k2]     = *(const ushort8*)(hrow);
      *(ushort8*)&Bhs[r * 40 + k2 + 8] = *(const ushort8*)(hrow + 8);
    }
    __syncthreads();

    short8 fa[2], fbz[NI], fbh[NI];
    #pragma unroll
    for (int mi = 0; mi < 2; mi++)
      fa[mi] = *(const short8*)&As[(wid * 32 + mi * 16 + l15) * 40 + lg * 8];
    #pragma unroll
    for (int ni = 0; ni < NI; ni++) {
      fbz[ni] = *(const short8*)&Bzs[(ni * 16 + l15) * 40 + lg * 8];
      fbh[ni] = *(const short8*)&Bhs[(ni * 16 + l15) * 40 + lg * 8];
    }
    #pragma unroll
    for (int mi = 0; mi < 2; mi++)
      #pragma unroll
      for (int ni = 0; ni < NI; ni++) {
        accz[mi][ni] = __builtin_amdgcn_mfma_f32_16x16x32_bf16(fa[mi], fbz[ni], accz[mi][ni], 0, 0, 0);
        acch[mi][ni] = __builtin_amdgcn_mfma_f32_16x16x32_bf16(fa[mi], fbh[ni], acch[mi][ni], 0, 0, 0);
      }
  }

  #pragma unroll
  for (int ni = 0; ni < NI; ni++) {
    const int dloc = ni * 16 + l15;
    const float bzv = bz[dh0 + dloc];
    const float bhv = bh[dh0 + dloc];
    #pragma unroll
    for (int mi = 0; mi < 2; mi++) {
      const int rowb = rows0 + wid * 32 + mi * 16 + lg * 4;
      #pragma unroll
      for (int r = 0; r < 4; r++) {
        float zl = accz[mi][ni][r] + bzv;
        float z = 1.f / (1.f + __expf(-zl));
        float ht = acch[mi][ni][r] + bhv;
        float2 v; v.x = 1.f - z; v.y = z * ht;
        ab[(size_t)(rowb + r) * DH + dloc] = v;
      }
    }
  }
}

// pass1: per (b,chunk) block, DH threads: chunk-local (prodA, combinedB)
template<int DH>
__global__ void scan1(const float2* __restrict__ ab, float* __restrict__ Ap, float* __restrict__ Bs) {
  const int blk = blockIdx.x;            // b*NCH + c
  const int b = blk / NCH;
  const int c = blk % NCH;
  const int d = threadIdx.x;
  const float2* p = ab + ((size_t)(b * SEQ + c * CS)) * DH + d;
  float Ar = 1.f, Br = 0.f;
  #pragma unroll 8
  for (int i = 0; i < CS; i++) {
    float2 v = p[(size_t)i * DH];
    Br = Br * v.x + v.y;
    Ar *= v.x;
  }
  const int idx = blk * DH + d;
  Ap[idx] = Ar; Bs[idx] = Br;
}

// pass2: per (b,d) channel: serial over chunks -> carry-in per chunk + final h
template<int DH>
__global__ void scan2(const float* __restrict__ Ap, const float* __restrict__ Bs,
                      float* __restrict__ carry, float* __restrict__ hlast, int dh0) {
  const int g = blockIdx.x * 256 + threadIdx.x;   // 32*DH
  const int b = g / DH, d = g % DH;
  float h = 0.f;
  for (int c = 0; c < NCH; c++) {
    const int idx = (b * NCH + c) * DH + d;
    carry[idx] = h;
    h = Bs[idx] + Ap[idx] * h;
  }
  hlast[b * DIM + dh0 + d] = h;
}

// pass3 (layer 0 only): apply carries, write h1 bf16 [row][DIM]
template<int DH>
__global__ void scan3(const float2* __restrict__ ab, const float* __restrict__ carry,
                      u16* __restrict__ h1, int dh0) {
  const int blk = blockIdx.x;
  const int b = blk / NCH, c = blk % NCH;
  const int d = threadIdx.x;
  float h = carry[blk * DH + d];
  const float2* p = ab + ((size_t)(b * SEQ + c * CS)) * DH + d;
  u16* o = h1 + (size_t)(b * SEQ + c * CS) * DIM + dh0 + d;
  #pragma unroll 8
  for (int i = 0; i < CS; i++) {
    float2 v = p[(size_t)i * DH];
    h = v.x * h + v.y;
    o[(size_t)i * DIM] = f2bf(h);
  }
}

__global__ void cls_kernel(const float* __restrict__ hlast, const float* __restrict__ Wo,
                           const float* __restrict__ bo, float* __restrict__ out) {
  const int t = threadIdx.x;       // 256 = 32 b * 8 classes
  const int b = t >> 3, c = t & 7;
  float acc = bo[c];
  for (int d = 0; d < DIM; d++) acc += hlast[b * DIM + d] * Wo[d * 8 + c];
  out[t] = acc;
}

template<int DH>
static void run_all(const int* x, const float* emb, const float* Wz, const float* bz,
                    const float* Wh, const float* bh, const float* Wo, const float* bo,
                    float* out, char* ws, hipStream_t stream)
{
  const size_t abB = (size_t)ROWS * DH * sizeof(float2);
  float2* ab    = (float2*)ws;
  u16*    h1    = (u16*)(ws + abB);
  u16*    Wt    = (u16*)(ws + abB + 134217728ull);
  float*  Ap    = (float*)(ws + abB + 134217728ull + 524288ull);
  float*  Bs    = Ap + (size_t)32 * NCH * DH;
  float*  carry = Bs + (size_t)32 * NCH * DH;
  float*  hlast = carry + (size_t)32 * NCH * DH;

  wt_kernel<<<1024, 256, 0, stream>>>(Wz, Wh, Wt);

  const int npass = DIM / DH;
  for (int l = 0; l < 2; l++) {
    const u16* Wzt = Wt + (size_t)l * 65536;
    const u16* Wht = Wt + (size_t)(2 + l) * 65536;
    const float* bzl = bz + l * DIM;
    const float* bhl = bh + l * DIM;
    for (int p = 0; p < npass; p++) {
      const int dh0 = p * DH;
      if (l == 0)
        gemm_kernel<0, DH><<<ROWS / 128, 256, 0, stream>>>(x, emb, h1, Wzt, Wht, bzl, bhl, dh0, ab);
      else
        gemm_kernel<1, DH><<<ROWS / 128, 256, 0, stream>>>(x, emb, h1, Wzt, Wht, bzl, bhl, dh0, ab);
      scan1<DH><<<BATCH * NCH, DH, 0, stream>>>(ab, Ap, Bs);
      scan2<DH><<<(32 * DH + 255) / 256, 256, 0, stream>>>(Ap, Bs, carry, hlast, dh0);
      if (l == 0)
        scan3<DH><<<BATCH * NCH, DH, 0, stream>>>(ab, carry, h1, dh0);
    }
  }

  cls_kernel<<<1, 256, 0, stream>>>(hlast, Wo, bo, out);
}

extern "C" void kernel_launch(void* const* d_in, const int* in_sizes, int n_in,
                              void* d_out, int out_size, void* d_ws, size_t ws_size,
                              hipStream_t stream) {
  (void)in_sizes; (void)n_in; (void)out_size;
  const int*   x   = (const int*)d_in[0];
  const float* emb = (const float*)d_in[1];
  const float* Wz  = (const float*)d_in[2];
  const float* bz  = (const float*)d_in[3];
  const float* Wh  = (const float*)d_in[4];
  const float* bh  = (const float*)d_in[5];
  const float* Wo  = (const float*)d_in[6];
  const float* bo  = (const float*)d_in[7];
  float* out = (float*)d_out;
  char* ws = (char*)d_ws;

  auto need = [](int DH) -> size_t {
    return (size_t)ROWS * DH * 8ull      // ab
         + 134217728ull                  // h1 bf16
         + 524288ull                     // Wt
         + 3ull * 32 * NCH * DH * 4ull   // Ap, Bs, carry
         + 32768ull;                     // hlast
  };

  if (ws_size >= need(64))
    run_all<64>(x, emb, Wz, bz, Wh, bh, Wo, bo, out, ws, stream);
  else if (ws_size >= need(32))
    run_all<32>(x, emb, Wz, bz, Wh, bh, Wo, bo, out, ws, stream);
  else
    run_all<16>(x, emb, Wz, bz, Wh, bh, Wo, bo, out, ws, stream);
}

// Round 3
// 500.058 us; speedup vs baseline: 2.2649x; 2.2649x over previous
//
#include <hip/hip_runtime.h>
#include <stdint.h>

#define DIM 256
#define SEQ 8192
#define BATCH 32
#define ROWS (BATCH * SEQ)    // 262144
#define CS 128                // scan chunk length == GEMM row tile
#define NCH (SEQ / CS)        // 64 chunks per sequence

typedef float f32x4 __attribute__((ext_vector_type(4)));
typedef short short8 __attribute__((ext_vector_type(8)));
typedef unsigned short u16;
typedef u16 ushort8 __attribute__((ext_vector_type(8)));

__device__ __forceinline__ u16 f2bf(float f) {
  uint32_t u = __float_as_uint(f);
  u += 0x7fffu + ((u >> 16) & 1u);   // round-to-nearest-even
  return (u16)(u >> 16);
}
__device__ __forceinline__ float bf2f(uint32_t lo16) {
  return __uint_as_float(lo16 << 16);
}

// One-time: W[l][k][d] f32 -> Wt[mat][d][k] bf16, mat = {Wz l0, Wz l1, Wh l0, Wh l1}
__global__ void wt_kernel(const float* __restrict__ Wz, const float* __restrict__ Wh,
                          u16* __restrict__ Wt) {
  int idx = blockIdx.x * 256 + threadIdx.x;   // 4*65536
  int k = idx & 255;
  int d = (idx >> 8) & 255;
  int mat = idx >> 16;
  const float* src = (mat < 2 ? Wz : Wh) + (size_t)(mat & 1) * 65536;
  Wt[idx] = f2bf(src[k * 256 + d]);
}

// ---------------- Layer 0 GEMM: emb-gather A, packed-bf16 ab output ----------------
// 128-row tile x (DH z + DH h cols), K=256. 4 waves x 32 rows.
// Epilogue: a=1-sigmoid(z+bz), b=sigmoid(z+bz)*(ht+bh) -> ab[row][dloc] = bf16(a) | bf16(b)<<16
template<int DH>
__global__ __launch_bounds__(256, 2)
void gemm0_kernel(const int* __restrict__ x, const float* __restrict__ emb,
                  const u16* __restrict__ Wzt, const u16* __restrict__ Wht,
                  const float* __restrict__ bz, const float* __restrict__ bh,
                  int dh0, uint32_t* __restrict__ ab)
{
  constexpr int NI = DH / 16;
  __shared__ __align__(16) u16 As[128 * 40];
  __shared__ __align__(16) u16 Bzs[DH * 40];
  __shared__ __align__(16) u16 Bhs[DH * 40];
  __shared__ int toks[128];

  const int tid = threadIdx.x;
  const int lane = tid & 63;
  const int wid = tid >> 6;
  const int rows0 = blockIdx.x * 128;
  const int sm = tid >> 1;
  const int sk = (tid & 1) * 16;
  const int l15 = lane & 15, lg = lane >> 4;

  if (tid < 128) toks[tid] = x[rows0 + tid];

  f32x4 accz[2][NI], acch[2][NI];
  #pragma unroll
  for (int i = 0; i < 2; i++)
    #pragma unroll
    for (int j = 0; j < NI; j++) {
      f32x4 zz = {0.f, 0.f, 0.f, 0.f};
      accz[i][j] = zz; acch[i][j] = zz;
    }

  for (int kt = 0; kt < 8; kt++) {
    const int kk0 = kt * 32;
    __syncthreads();
    {
      const float* arow = emb + (size_t)toks[sm] * DIM + kk0 + sk;
      float4 a0 = *(const float4*)(arow + 0);
      float4 a1 = *(const float4*)(arow + 4);
      float4 a2 = *(const float4*)(arow + 8);
      float4 a3 = *(const float4*)(arow + 12);
      ushort8 p0, p1;
      p0[0]=f2bf(a0.x); p0[1]=f2bf(a0.y); p0[2]=f2bf(a0.z); p0[3]=f2bf(a0.w);
      p0[4]=f2bf(a1.x); p0[5]=f2bf(a1.y); p0[6]=f2bf(a1.z); p0[7]=f2bf(a1.w);
      p1[0]=f2bf(a2.x); p1[1]=f2bf(a2.y); p1[2]=f2bf(a2.z); p1[3]=f2bf(a2.w);
      p1[4]=f2bf(a3.x); p1[5]=f2bf(a3.y); p1[6]=f2bf(a3.z); p1[7]=f2bf(a3.w);
      *(ushort8*)&As[sm * 40 + sk]     = p0;
      *(ushort8*)&As[sm * 40 + sk + 8] = p1;
    }
    if (tid < 2 * DH) {
      const int r = tid >> 1, k2 = (tid & 1) * 16;
      const u16* zrow = Wzt + (size_t)(dh0 + r) * DIM + kk0 + k2;
      *(ushort8*)&Bzs[r * 40 + k2]     = *(const ushort8*)(zrow);
      *(ushort8*)&Bzs[r * 40 + k2 + 8] = *(const ushort8*)(zrow + 8);
    } else if (tid < 4 * DH) {
      const int t2 = tid - 2 * DH;
      const int r = t2 >> 1, k2 = (t2 & 1) * 16;
      const u16* hrow = Wht + (size_t)(dh0 + r) * DIM + kk0 + k2;
      *(ushort8*)&Bhs[r * 40 + k2]     = *(const ushort8*)(hrow);
      *(ushort8*)&Bhs[r * 40 + k2 + 8] = *(const ushort8*)(hrow + 8);
    }
    __syncthreads();

    short8 fa[2];
    #pragma unroll
    for (int mi = 0; mi < 2; mi++)
      fa[mi] = *(const short8*)&As[(wid * 32 + mi * 16 + l15) * 40 + lg * 8];
    #pragma unroll
    for (int ni = 0; ni < NI; ni++) {
      short8 fbz = *(const short8*)&Bzs[(ni * 16 + l15) * 40 + lg * 8];
      short8 fbh = *(const short8*)&Bhs[(ni * 16 + l15) * 40 + lg * 8];
      #pragma unroll
      for (int mi = 0; mi < 2; mi++) {
        accz[mi][ni] = __builtin_amdgcn_mfma_f32_16x16x32_bf16(fa[mi], fbz, accz[mi][ni], 0, 0, 0);
        acch[mi][ni] = __builtin_amdgcn_mfma_f32_16x16x32_bf16(fa[mi], fbh, acch[mi][ni], 0, 0, 0);
      }
    }
  }

  #pragma unroll
  for (int ni = 0; ni < NI; ni++) {
    const int dloc = ni * 16 + l15;
    const float bzv = bz[dh0 + dloc];
    const float bhv = bh[dh0 + dloc];
    #pragma unroll
    for (int mi = 0; mi < 2; mi++) {
      const int rowb = rows0 + wid * 32 + mi * 16 + lg * 4;
      #pragma unroll
      for (int r = 0; r < 4; r++) {
        float zl = accz[mi][ni][r] + bzv;
        float z = 1.f / (1.f + __expf(-zl));
        float ht = acch[mi][ni][r] + bhv;
        uint32_t pk = (uint32_t)f2bf(1.f - z) | ((uint32_t)f2bf(z * ht) << 16);
        ab[(size_t)(rowb + r) * DH + dloc] = pk;
      }
    }
  }
}

// ---------------- Layer 1: fused GEMM + chunk-scan (no ab buffer) ----------------
// Block == one chunk (b,c) of 128 timesteps. DH=128 cols per pass.
// After MFMA: ordered affine composition (A=prod a, B = scan-combined b) per column,
// in-lane (4 steps) -> shfl_xor butterfly (lane groups) -> LDS (waves) -> Ap/Bs.
template<int DH>
__global__ __launch_bounds__(256, 2)
void gemm1_scan_kernel(const u16* __restrict__ h1,
                       const u16* __restrict__ Wzt, const u16* __restrict__ Wht,
                       const float* __restrict__ bz, const float* __restrict__ bh,
                       int dh0, float* __restrict__ Ap, float* __restrict__ Bs)
{
  constexpr int NI = DH / 16;
  __shared__ __align__(16) u16 As[128 * 40];
  __shared__ __align__(16) u16 Bzs[DH * 40];
  __shared__ __align__(16) u16 Bhs[DH * 40];
  __shared__ float wtA[4][DH];
  __shared__ float wtB[4][DH];

  const int tid = threadIdx.x;
  const int lane = tid & 63;
  const int wid = tid >> 6;
  const int rows0 = blockIdx.x * 128;
  const int sm = tid >> 1;
  const int sk = (tid & 1) * 16;
  const int l15 = lane & 15, lg = lane >> 4;

  f32x4 accz[2][NI], acch[2][NI];
  #pragma unroll
  for (int i = 0; i < 2; i++)
    #pragma unroll
    for (int j = 0; j < NI; j++) {
      f32x4 zz = {0.f, 0.f, 0.f, 0.f};
      accz[i][j] = zz; acch[i][j] = zz;
    }

  for (int kt = 0; kt < 8; kt++) {
    const int kk0 = kt * 32;
    __syncthreads();
    {
      const u16* arow = h1 + (size_t)(rows0 + sm) * DIM + kk0 + sk;
      *(ushort8*)&As[sm * 40 + sk]     = *(const ushort8*)(arow);
      *(ushort8*)&As[sm * 40 + sk + 8] = *(const ushort8*)(arow + 8);
    }
    {
      const int r = tid >> 1, k2 = (tid & 1) * 16;   // r covers 0..127 (DH=128)
      const u16* zrow = Wzt + (size_t)(dh0 + r) * DIM + kk0 + k2;
      *(ushort8*)&Bzs[r * 40 + k2]     = *(const ushort8*)(zrow);
      *(ushort8*)&Bzs[r * 40 + k2 + 8] = *(const ushort8*)(zrow + 8);
      const u16* hrow = Wht + (size_t)(dh0 + r) * DIM + kk0 + k2;
      *(ushort8*)&Bhs[r * 40 + k2]     = *(const ushort8*)(hrow);
      *(ushort8*)&Bhs[r * 40 + k2 + 8] = *(const ushort8*)(hrow + 8);
    }
    __syncthreads();

    short8 fa[2];
    #pragma unroll
    for (int mi = 0; mi < 2; mi++)
      fa[mi] = *(const short8*)&As[(wid * 32 + mi * 16 + l15) * 40 + lg * 8];
    #pragma unroll
    for (int ni = 0; ni < NI; ni++) {
      short8 fbz = *(const short8*)&Bzs[(ni * 16 + l15) * 40 + lg * 8];
      short8 fbh = *(const short8*)&Bhs[(ni * 16 + l15) * 40 + lg * 8];
      #pragma unroll
      for (int mi = 0; mi < 2; mi++) {
        accz[mi][ni] = __builtin_amdgcn_mfma_f32_16x16x32_bf16(fa[mi], fbz, accz[mi][ni], 0, 0, 0);
        acch[mi][ni] = __builtin_amdgcn_mfma_f32_16x16x32_bf16(fa[mi], fbh, acch[mi][ni], 0, 0, 0);
      }
    }
  }

  // ---- fused chunk scan ----
  const int b = blockIdx.x >> 6;        // NCH = 64
  const int c = blockIdx.x & 63;

  #pragma unroll
  for (int ni = 0; ni < NI; ni++) {
    const int dloc = ni * 16 + l15;
    const float bzv = bz[dh0 + dloc];
    const float bhv = bh[dh0 + dloc];
    float At[2], Bt[2];
    // in-lane: 4 consecutive timesteps per mi segment
    #pragma unroll
    for (int mi = 0; mi < 2; mi++) {
      float A = 1.f, B = 0.f;
      #pragma unroll
      for (int r = 0; r < 4; r++) {
        float zl = accz[mi][ni][r] + bzv;
        float z = 1.f / (1.f + __expf(-zl));
        float ht = acch[mi][ni][r] + bhv;
        float a = 1.f - z, bb = z * ht;
        B = B * a + bb;
        A = A * a;
      }
      At[mi] = A; Bt[mi] = B;
    }
    // butterfly compose across lane-groups (bits 4,5 of lane = 4-step segment index)
    #pragma unroll
    for (int mi = 0; mi < 2; mi++) {
      float A = At[mi], B = Bt[mi];
      #pragma unroll
      for (int s = 16; s <= 32; s <<= 1) {
        float A2 = __shfl_xor(A, s);
        float B2 = __shfl_xor(B, s);
        if ((lane & s) == 0) {   // self earlier: (self, other)
          B = B * A2 + B2;
          A = A * A2;
        } else {                 // other earlier: (other, self)
          B = B2 * A + B;
          A = A2 * A;
        }
      }
      At[mi] = A; Bt[mi] = B;
    }
    // compose mi0 (rows 0..15) then mi1 (rows 16..31)
    float Aw = At[0] * At[1];
    float Bw = Bt[0] * At[1] + Bt[1];
    if (lg == 0) { wtA[wid][dloc] = Aw; wtB[wid][dloc] = Bw; }
  }

  __syncthreads();
  if (tid < DH) {
    float A = wtA[0][tid], B = wtB[0][tid];
    #pragma unroll
    for (int w = 1; w < 4; w++) {
      float A2 = wtA[w][tid], B2 = wtB[w][tid];
      B = B * A2 + B2;
      A = A * A2;
    }
    const int idx = (b * NCH + c) * DIM + dh0 + tid;
    Ap[idx] = A; Bs[idx] = B;
  }
}

// ---------------- Layer 0 scan passes (packed bf16 ab) ----------------
template<int DH>
__global__ void scan1(const uint32_t* __restrict__ ab, float* __restrict__ Ap, float* __restrict__ Bs) {
  const int blk = blockIdx.x;            // b*NCH + c
  const int b = blk / NCH;
  const int c = blk % NCH;
  const int d = threadIdx.x;
  const uint32_t* p = ab + ((size_t)(b * SEQ + c * CS)) * DH + d;
  float Ar = 1.f, Br = 0.f;
  #pragma unroll 8
  for (int i = 0; i < CS; i++) {
    uint32_t u = p[(size_t)i * DH];
    float a = bf2f(u & 0xffffu), bb = bf2f(u >> 16);
    Br = Br * a + bb;
    Ar *= a;
  }
  const int idx = blk * DH + d;
  Ap[idx] = Ar; Bs[idx] = Br;
}

template<int DH>
__global__ void scan2(const float* __restrict__ Ap, const float* __restrict__ Bs,
                      float* __restrict__ carry) {
  const int g = blockIdx.x * 256 + threadIdx.x;   // 32*DH
  const int b = g / DH, d = g % DH;
  float h = 0.f;
  for (int c = 0; c < NCH; c++) {
    const int idx = (b * NCH + c) * DH + d;
    carry[idx] = h;
    h = Bs[idx] + Ap[idx] * h;
  }
}

template<int DH>
__global__ void scan3(const uint32_t* __restrict__ ab, const float* __restrict__ carry,
                      u16* __restrict__ h1, int dh0) {
  const int blk = blockIdx.x;
  const int b = blk / NCH, c = blk % NCH;
  const int d = threadIdx.x;
  float h = carry[blk * DH + d];
  const uint32_t* p = ab + ((size_t)(b * SEQ + c * CS)) * DH + d;
  u16* o = h1 + (size_t)(b * SEQ + c * CS) * DIM + dh0 + d;
  #pragma unroll 8
  for (int i = 0; i < CS; i++) {
    uint32_t u = p[(size_t)i * DH];
    float a = bf2f(u & 0xffffu), bb = bf2f(u >> 16);
    h = a * h + bb;
    o[(size_t)i * DIM] = f2bf(h);
  }
}

// layer-1 final: serial over 64 chunks for all 256 d -> hlast
__global__ void scan2_l1(const float* __restrict__ Ap, const float* __restrict__ Bs,
                         float* __restrict__ hlast) {
  const int g = blockIdx.x * 256 + threadIdx.x;   // 8192 = 32 b * 256 d
  const int b = g >> 8, d = g & 255;
  float h = 0.f;
  for (int c = 0; c < NCH; c++) {
    const int idx = (b * NCH + c) * DIM + d;
    h = Bs[idx] + Ap[idx] * h;
  }
  hlast[b * DIM + d] = h;
}

__global__ void cls_kernel(const float* __restrict__ hlast, const float* __restrict__ Wo,
                           const float* __restrict__ bo, float* __restrict__ out) {
  const int t = threadIdx.x;       // 256 = 32 b * 8 classes
  const int b = t >> 3, c = t & 7;
  float acc = bo[c];
  for (int d = 0; d < DIM; d++) acc += hlast[b * DIM + d] * Wo[d * 8 + c];
  out[t] = acc;
}

template<int DHL0>
static void run_all(const int* x, const float* emb, const float* Wz, const float* bz,
                    const float* Wh, const float* bh, const float* Wo, const float* bo,
                    float* out, char* ws, hipStream_t stream)
{
  const size_t abB = (size_t)ROWS * DHL0 * 4ull;
  uint32_t* ab    = (uint32_t*)ws;
  u16*      h1    = (u16*)(ws + abB);
  u16*      Wt    = (u16*)(ws + abB + 134217728ull);
  float*    Ap    = (float*)(ws + abB + 134217728ull + 524288ull);
  float*    Bs    = Ap + (size_t)32 * NCH * DIM;                 // 2 MB stride (max layout)
  float*    carry = Bs + (size_t)32 * NCH * DIM;
  float*    hlast = carry + (size_t)32 * NCH * DHL0;

  wt_kernel<<<1024, 256, 0, stream>>>(Wz, Wh, Wt);

  // ---- layer 0: DHL0-sliced, packed-bf16 ab ----
  {
    const u16* Wzt = Wt;                       // Wz l0
    const u16* Wht = Wt + (size_t)2 * 65536;   // Wh l0
    const int npass = DIM / DHL0;
    for (int p = 0; p < npass; p++) {
      const int dh0 = p * DHL0;
      gemm0_kernel<DHL0><<<ROWS / 128, 256, 0, stream>>>(x, emb, Wzt, Wht, bz, bh, dh0, ab);
      scan1<DHL0><<<BATCH * NCH, DHL0, 0, stream>>>(ab, Ap, Bs);
      scan2<DHL0><<<(32 * DHL0 + 255) / 256, 256, 0, stream>>>(Ap, Bs, carry);
      scan3<DHL0><<<BATCH * NCH, DHL0, 0, stream>>>(ab, carry, h1, dh0);
    }
  }

  // ---- layer 1: fused GEMM+scan, DH=128 x 2 passes, no ab ----
  {
    const u16* Wzt = Wt + (size_t)1 * 65536;   // Wz l1
    const u16* Wht = Wt + (size_t)3 * 65536;   // Wh l1
    gemm1_scan_kernel<128><<<ROWS / 128, 256, 0, stream>>>(h1, Wzt, Wht, bz + DIM, bh + DIM, 0, Ap, Bs);
    gemm1_scan_kernel<128><<<ROWS / 128, 256, 0, stream>>>(h1, Wzt, Wht, bz + DIM, bh + DIM, 128, Ap, Bs);
    scan2_l1<<<32, 256, 0, stream>>>(Ap, Bs, hlast);
  }

  cls_kernel<<<1, 256, 0, stream>>>(hlast, Wo, bo, out);
}

extern "C" void kernel_launch(void* const* d_in, const int* in_sizes, int n_in,
                              void* d_out, int out_size, void* d_ws, size_t ws_size,
                              hipStream_t stream) {
  (void)in_sizes; (void)n_in; (void)out_size;
  const int*   x   = (const int*)d_in[0];
  const float* emb = (const float*)d_in[1];
  const float* Wz  = (const float*)d_in[2];
  const float* bz  = (const float*)d_in[3];
  const float* Wh  = (const float*)d_in[4];
  const float* bh  = (const float*)d_in[5];
  const float* Wo  = (const float*)d_in[6];
  const float* bo  = (const float*)d_in[7];
  float* out = (float*)d_out;
  char* ws = (char*)d_ws;

  auto need = [](int DHL0) -> size_t {
    return (size_t)ROWS * DHL0 * 4ull        // ab (packed bf16 pair)
         + 134217728ull                      // h1 bf16
         + 524288ull                         // Wt
         + 2ull * 32 * NCH * DIM * 4ull      // Ap, Bs (sized for layer-1 layout)
         + (size_t)32 * NCH * DHL0 * 4ull    // carry
         + 32768ull;                         // hlast
  };

  if (ws_size >= need(64))
    run_all<64>(x, emb, Wz, bz, Wh, bh, Wo, bo, out, ws, stream);
  else
    run_all<32>(x, emb, Wz, bz, Wh, bh, Wo, bo, out, ws, stream);
}

// Round 5
// 454.668 us; speedup vs baseline: 2.4910x; 1.0998x over previous
//
#include <hip/hip_runtime.h>
#include <stdint.h>

#define DIM 256
#define SEQ 8192
#define BATCH 32
#define QB 8                       // batches per quarter
#define QROWS (QB * SEQ)           // 65536
#define CS 128                     // chunk length == GEMM row tile
#define NCH (SEQ / CS)             // 64 chunks per sequence

typedef float f32x4 __attribute__((ext_vector_type(4)));
typedef short short8 __attribute__((ext_vector_type(8)));
typedef unsigned short u16;
typedef u16 ushort8 __attribute__((ext_vector_type(8)));

__device__ __forceinline__ u16 f2bf(float f) {
  uint32_t u = __float_as_uint(f);
  u += 0x7fffu + ((u >> 16) & 1u);   // round-to-nearest-even
  return (u16)(u >> 16);
}
__device__ __forceinline__ float bf2f(uint32_t lo16) {
  return __uint_as_float(lo16 << 16);
}

// async 16B global->LDS (lds dest wave-uniform base; HW adds lane*16)
__device__ __forceinline__ void gld16(void* lds, const void* g) {
  __builtin_amdgcn_global_load_lds(
      (const __attribute__((address_space(1))) uint32_t*)g,
      (__attribute__((address_space(3))) uint32_t*)lds, 16, 0, 0);
}

// ---------- weight preprocess: f32 [l][k][d] -> bf16 swizzled 8KB tiles ----------
// WtS: 64 tiles of 8192 BYTES, tile index (mat*4 + dh)*4 + kt, in-tile [64 dloc][64 kl],
// byte = (dloc*128 + kl*2) ^ ((dloc&7)<<4).  mat: 0=Wz l0,1=Wz l1,2=Wh l0,3=Wh l1
__global__ void wt_kernel(const float* __restrict__ Wz, const float* __restrict__ Wh,
                          u16* __restrict__ WtS) {
  int idx = blockIdx.x * 256 + threadIdx.x;   // 4*65536
  int d = idx & 255;
  int k = (idx >> 8) & 255;
  int m = idx >> 16;
  const float* src = (m < 2 ? Wz : Wh) + (size_t)(m & 1) * 65536;
  float v = src[k * 256 + d];
  int dh = d >> 6, dloc = d & 63, kt = k >> 6, kl = k & 63;
  size_t tile = ((size_t)(m * 4 + dh) * 4 + kt) * 8192;   // BYTES
  size_t byte = (size_t)((dloc * 128 + kl * 2) ^ ((dloc & 7) << 4));
  *(u16*)((char*)WtS + tile + byte) = f2bf(v);
}

// ---------- GEMM + fused chunk-scan ----------
// Block: 128 rows (one chunk) x 64 d-slice (z + h), K=256, BK=64. grid=(512, 4dh).
// MODE 0: A = emb[x[row]] gather (reg-staged, swizzled ds_write); writes packed ab.
// MODE 1: A = h1q (pre-swizzled bf16 16KB tiles, global_load_lds verbatim).
template<int MODE>
__global__ __launch_bounds__(256, 3)
void gemm_kernel(const int* __restrict__ xq, const float* __restrict__ emb,
                 const u16* __restrict__ h1q, const u16* __restrict__ WtS, int lsel,
                 const float* __restrict__ bzl, const float* __restrict__ bhl,
                 uint32_t* __restrict__ ab, float* __restrict__ Ap, float* __restrict__ Bs)
{
  __shared__ __align__(16) u16 As[8192];    // 16KB: [128 t][64 k] swizzled
  __shared__ __align__(16) u16 Bzs[4096];   // 8KB:  [64 d][64 k] swizzled
  __shared__ __align__(16) u16 Bhs[4096];
  __shared__ float wtA[4][64], wtB[4][64];
  __shared__ int toks[128];

  const int tid = threadIdx.x;
  const int lane = tid & 63;
  const int w = tid >> 6;
  const int l15 = lane & 15, lg = lane >> 4;
  const int rows0 = blockIdx.x * 128;
  const int dh0 = blockIdx.y * 64;

  if (MODE == 0 && tid < 128) toks[tid] = xq[rows0 + tid];

  // BYTE-based tile addressing (8KB weight tiles; 16KB h1 tiles)
  const char* bzmat = (const char*)WtS + (size_t)(lsel * 4 + blockIdx.y) * 4 * 8192;
  const char* bhmat = (const char*)WtS + (size_t)((2 + lsel) * 4 + blockIdx.y) * 4 * 8192;
  const char* amat  = (MODE == 1) ? ((const char*)h1q + (size_t)blockIdx.x * 65536) : nullptr;

  f32x4 accz[2][4], acch[2][4];
  #pragma unroll
  for (int i = 0; i < 2; i++)
    #pragma unroll
    for (int j = 0; j < 4; j++) {
      f32x4 zz = {0.f, 0.f, 0.f, 0.f};
      accz[i][j] = zz; acch[i][j] = zz;
    }

  for (int kt = 0; kt < 4; kt++) {
    __syncthreads();
    // ---- stage B: verbatim copy of swizzled 8KB tiles ----
    {
      const char* gz = bzmat + (size_t)kt * 8192;
      const char* gh = bhmat + (size_t)kt * 8192;
      #pragma unroll
      for (int i = 0; i < 2; i++) {
        gld16((char*)Bzs + w * 2048 + i * 1024, gz + w * 2048 + i * 1024 + lane * 16);
        gld16((char*)Bhs + w * 2048 + i * 1024, gh + w * 2048 + i * 1024 + lane * 16);
      }
    }
    // ---- stage A ----
    if (MODE == 1) {
      const char* ga = amat + (size_t)kt * 16384;
      #pragma unroll
      for (int i = 0; i < 4; i++)
        gld16((char*)As + w * 4096 + i * 1024, ga + w * 4096 + i * 1024 + lane * 16);
    } else {
      const int sm = tid >> 1;
      const int skb = (tid & 1) * 64;           // byte offset of 32-short half
      const float* arow = emb + (size_t)toks[sm] * 256 + kt * 64 + (tid & 1) * 32;
      #pragma unroll
      for (int j = 0; j < 4; j++) {
        float4 a0 = *(const float4*)(arow + j * 8);
        float4 a1 = *(const float4*)(arow + j * 8 + 4);
        ushort8 p;
        p[0]=f2bf(a0.x); p[1]=f2bf(a0.y); p[2]=f2bf(a0.z); p[3]=f2bf(a0.w);
        p[4]=f2bf(a1.x); p[5]=f2bf(a1.y); p[6]=f2bf(a1.z); p[7]=f2bf(a1.w);
        *(ushort8*)((char*)As + ((sm * 128 + skb + j * 16) ^ ((sm & 7) << 4))) = p;
      }
    }
    __syncthreads();

    // ---- compute: 2 k-substeps of 32 ----
    #pragma unroll
    for (int ks = 0; ks < 2; ks++) {
      short8 fa[2], fbz[4], fbh[4];
      const int xm = (l15 & 7) << 4;
      #pragma unroll
      for (int mi = 0; mi < 2; mi++)
        fa[mi] = *(const short8*)((const char*)As +
                   (((w * 32 + mi * 16 + l15) * 128 + ks * 64 + lg * 16) ^ xm));
      #pragma unroll
      for (int ni = 0; ni < 4; ni++) {
        fbz[ni] = *(const short8*)((const char*)Bzs +
                   (((ni * 16 + l15) * 128 + ks * 64 + lg * 16) ^ xm));
        fbh[ni] = *(const short8*)((const char*)Bhs +
                   (((ni * 16 + l15) * 128 + ks * 64 + lg * 16) ^ xm));
      }
      #pragma unroll
      for (int mi = 0; mi < 2; mi++)
        #pragma unroll
        for (int ni = 0; ni < 4; ni++) {
          accz[mi][ni] = __builtin_amdgcn_mfma_f32_16x16x32_bf16(fa[mi], fbz[ni], accz[mi][ni], 0, 0, 0);
          acch[mi][ni] = __builtin_amdgcn_mfma_f32_16x16x32_bf16(fa[mi], fbh[ni], acch[mi][ni], 0, 0, 0);
        }
    }
  }

  // ---- epilogue: gate + (MODE0) ab write + fused chunk compose ----
  #pragma unroll
  for (int ni = 0; ni < 4; ni++) {
    const int dloc = ni * 16 + l15;
    const float bzv = bzl[dh0 + dloc];
    const float bhv = bhl[dh0 + dloc];
    float At[2], Bt[2];
    #pragma unroll
    for (int mi = 0; mi < 2; mi++) {
      float A = 1.f, B = 0.f;
      #pragma unroll
      for (int r = 0; r < 4; r++) {
        float zl = accz[mi][ni][r] + bzv;
        float z = 1.f / (1.f + __expf(-zl));
        float ht = acch[mi][ni][r] + bhv;
        float a = 1.f - z, bb = z * ht;
        if (MODE == 0) {
          uint32_t pk = (uint32_t)f2bf(a) | ((uint32_t)f2bf(bb) << 16);
          ab[(size_t)(rows0 + w * 32 + mi * 16 + lg * 4 + r) * 256 + dh0 + dloc] = pk;
        }
        B = B * a + bb;
        A *= a;
      }
      At[mi] = A; Bt[mi] = B;
    }
    #pragma unroll
    for (int mi = 0; mi < 2; mi++) {
      float A = At[mi], B = Bt[mi];
      #pragma unroll
      for (int s = 16; s <= 32; s <<= 1) {
        float A2 = __shfl_xor(A, s);
        float B2 = __shfl_xor(B, s);
        if ((lane & s) == 0) { B = B * A2 + B2; A = A * A2; }
        else                 { B = B2 * A + B;  A = A2 * A; }
      }
      At[mi] = A; Bt[mi] = B;
    }
    float Aw = At[0] * At[1];
    float Bw = Bt[0] * At[1] + Bt[1];
    if (lg == 0) { wtA[w][dloc] = Aw; wtB[w][dloc] = Bw; }
  }
  __syncthreads();
  if (tid < 64) {
    float A = wtA[0][tid], B = wtB[0][tid];
    #pragma unroll
    for (int ww = 1; ww < 4; ww++) {
      float A2 = wtA[ww][tid], B2 = wtB[ww][tid];
      B = B * A2 + B2;
      A = A * A2;
    }
    const int idx = blockIdx.x * 256 + dh0 + tid;
    Ap[idx] = A; Bs[idx] = B;
  }
}

// ---------- layer-0 cross-chunk carries (per quarter) ----------
__global__ void scan2_l0(const float* __restrict__ Ap, const float* __restrict__ Bs,
                         float* __restrict__ carry) {
  const int g = blockIdx.x * 256 + threadIdx.x;   // 2048 = 8 qb * 256 d
  const int qb = g >> 8, d = g & 255;
  float h = 0.f;
  for (int c = 0; c < NCH; c++) {
    const int idx = (qb * NCH + c) * 256 + d;
    carry[idx] = h;
    h = Bs[idx] + Ap[idx] * h;
  }
}

// ---------- apply carries, write h1 as pre-swizzled bf16 16KB tiles ----------
// h1q: [chunk(512)][kt(4)] tiles of 16384 BYTES, byte = (t*128 + kl*2) ^ ((t&7)<<4)
__global__ void scan3_kernel(const uint32_t* __restrict__ ab, const float* __restrict__ carry,
                             u16* __restrict__ h1q) {
  const int blk = blockIdx.x;          // chunk = qb*64 + c
  const int td = threadIdx.x;          // 0..127 -> channel pair (2td, 2td+1)
  float h0 = carry[blk * 256 + 2 * td];
  float h1v = carry[blk * 256 + 2 * td + 1];
  const uint2* p = (const uint2*)ab + (size_t)blk * 16384 + td;
  char* tile = (char*)h1q + (size_t)blk * 65536 + (size_t)(td >> 5) * 16384;
  const int klb = (td & 31) * 4;
  #pragma unroll 8
  for (int t = 0; t < CS; t++) {
    uint2 v = p[(size_t)t * 128];
    float a0 = bf2f(v.x & 0xffffu), b0 = bf2f(v.x >> 16);
    float a1 = bf2f(v.y & 0xffffu), b1 = bf2f(v.y >> 16);
    h0 = a0 * h0 + b0;
    h1v = a1 * h1v + b1;
    uint32_t pk = (uint32_t)f2bf(h0) | ((uint32_t)f2bf(h1v) << 16);
    *(uint32_t*)(tile + ((t * 128 + klb) ^ ((t & 7) << 4))) = pk;
  }
}

// ---------- layer-1 final: serial over chunks -> hlast ----------
__global__ void scan2_l1(const float* __restrict__ Ap, const float* __restrict__ Bs,
                         float* __restrict__ hlast) {
  const int g = blockIdx.x * 256 + threadIdx.x;   // 8192 = 32 b * 256 d
  const int b = g >> 8, d = g & 255;
  float h = 0.f;
  for (int c = 0; c < NCH; c++) {
    const int idx = (b * NCH + c) * 256 + d;
    h = Bs[idx] + Ap[idx] * h;
  }
  hlast[b * 256 + d] = h;
}

__global__ void cls_kernel(const float* __restrict__ hlast, const float* __restrict__ Wo,
                           const float* __restrict__ bo, float* __restrict__ out) {
  const int t = threadIdx.x;       // 256 = 32 b * 8 classes
  const int b = t >> 3, c = t & 7;
  float acc = bo[c];
  for (int d = 0; d < DIM; d++) acc += hlast[b * 256 + d] * Wo[d * 8 + c];
  out[t] = acc;
}

extern "C" void kernel_launch(void* const* d_in, const int* in_sizes, int n_in,
                              void* d_out, int out_size, void* d_ws, size_t ws_size,
                              hipStream_t stream) {
  (void)in_sizes; (void)n_in; (void)out_size; (void)ws_size;
  const int*   x   = (const int*)d_in[0];
  const float* emb = (const float*)d_in[1];
  const float* Wz  = (const float*)d_in[2];
  const float* bz  = (const float*)d_in[3];
  const float* Wh  = (const float*)d_in[4];
  const float* bh  = (const float*)d_in[5];
  const float* Wo  = (const float*)d_in[6];
  const float* bo  = (const float*)d_in[7];
  float* out = (float*)d_out;
  char* ws = (char*)d_ws;

  // workspace layout (total ~107 MB; round-3 proved ws >= 174 MB)
  uint32_t* ab    = (uint32_t*)(ws);                        //  67,108,864
  u16*      h1q   = (u16*)     (ws + 67108864ull);          //  33,554,432
  u16*      WtS   = (u16*)     (ws + 100663296ull);         //     524,288 (64 x 8KB tiles)
  float*    Ap0   = (float*)   (ws + 101187584ull);         //     524,288
  float*    Bs0   = (float*)   (ws + 101711872ull);         //     524,288
  float*    carry = (float*)   (ws + 102236160ull);         //     524,288
  float*    Ap1   = (float*)   (ws + 102760448ull);         //   2,097,152
  float*    Bs1   = (float*)   (ws + 104857600ull);         //   2,097,152
  float*    hlast = (float*)   (ws + 106954752ull);         //      32,768

  wt_kernel<<<1024, 256, 0, stream>>>(Wz, Wh, WtS);

  for (int q = 0; q < 4; q++) {
    const int* xq = x + (size_t)q * QROWS;
    gemm_kernel<0><<<dim3(512, 4), 256, 0, stream>>>(
        xq, emb, nullptr, WtS, 0, bz, bh, ab, Ap0, Bs0);
    scan2_l0<<<8, 256, 0, stream>>>(Ap0, Bs0, carry);
    scan3_kernel<<<512, 128, 0, stream>>>(ab, carry, h1q);
    gemm_kernel<1><<<dim3(512, 4), 256, 0, stream>>>(
        nullptr, nullptr, h1q, WtS, 1, bz + 256, bh + 256,
        nullptr, Ap1 + (size_t)q * 131072, Bs1 + (size_t)q * 131072);
  }

  scan2_l1<<<32, 256, 0, stream>>>(Ap1, Bs1, hlast);
  cls_kernel<<<1, 256, 0, stream>>>(hlast, Wo, bo, out);
}